// Round 1
// baseline (681.687 us; speedup 1.0000x reference)
//
#include <hip/hip_runtime.h>
#include <math.h>

// ---------------------------------------------------------------------------
// GAT 2-layer forward. N=100k nodes, E=1.6M edges + N self-loops.
// Strategy: build CSR-by-dst on device (hist -> scan -> scatter), then
// per-node wave aggregation (no float atomics, no segment-max needed since
// logits are O(1) and softmax is shift-invariant).
// ---------------------------------------------------------------------------

__global__ void k_init(int* __restrict__ cnt, int* __restrict__ cur, int n) {
    int i = blockIdx.x * blockDim.x + threadIdx.x;
    if (i < n) { cnt[i] = 1; cur[i] = 0; }   // cnt starts at 1: self-loop
}

__global__ void k_hist(const int* __restrict__ ei, int E, int* __restrict__ cnt) {
    int i = blockIdx.x * blockDim.x + threadIdx.x;
    if (i < E) atomicAdd(&cnt[ei[E + i]], 1);     // ei[1][i] = dst
}

// Per-block (chunk=2048) exclusive scan, block totals to bsum.
__global__ void k_scan1(const int* __restrict__ cnt, int* __restrict__ off,
                        int* __restrict__ bsum, int n) {
    __shared__ int lds[256];
    int t = threadIdx.x;
    int base = blockIdx.x * 2048 + t * 8;
    int v[8]; int s = 0;
#pragma unroll
    for (int j = 0; j < 8; ++j) { int idx = base + j; v[j] = (idx < n) ? cnt[idx] : 0; s += v[j]; }
    lds[t] = s; __syncthreads();
    int inc = s;
    for (int d = 1; d < 256; d <<= 1) {
        int y = (t >= d) ? lds[t - d] : 0;
        __syncthreads();
        inc += y; lds[t] = inc;
        __syncthreads();
    }
    int run = inc - s;
#pragma unroll
    for (int j = 0; j < 8; ++j) { int idx = base + j; if (idx < n) off[idx] = run; run += v[j]; }
    if (t == 255) bsum[blockIdx.x] = inc;
}

__global__ void k_scan2(int* __restrict__ bsum, int nb) {
    __shared__ int lds[1024];
    int t = threadIdx.x;
    int v = (t < nb) ? bsum[t] : 0;
    lds[t] = v; __syncthreads();
    int inc = v;
    for (int d = 1; d < 1024; d <<= 1) {
        int y = (t >= d) ? lds[t - d] : 0;
        __syncthreads();
        inc += y; lds[t] = inc;
        __syncthreads();
    }
    if (t < nb) bsum[t] = inc - v;   // exclusive block prefix
}

__global__ void k_scan3(int* __restrict__ off, const int* __restrict__ bsum, int n, int total) {
    int i = blockIdx.x * blockDim.x + threadIdx.x;
    if (i < n) off[i] += bsum[i / 2048];
    if (i == 0) off[n] = total;
}

__global__ void k_scatter(const int* __restrict__ ei, int E, int n,
                          const int* __restrict__ off, int* __restrict__ cur,
                          int* __restrict__ csr_src) {
    int i = blockIdx.x * blockDim.x + threadIdx.x;
    int total = E + n;
    if (i >= total) return;
    int s, d;
    if (i < E) { s = ei[i]; d = ei[E + i]; } else { s = d = i - E; }
    int pos = off[d] + atomicAdd(&cur[d], 1);
    csr_src[pos] = s;
}

// h1 = x @ W1  [N,64]; also attention logit halves as1/ad1 [N,2].
__global__ void k_gemm1(const float* __restrict__ x, const float* __restrict__ W1,
                        const float* __restrict__ a_src1, const float* __restrict__ a_dst1,
                        float* __restrict__ h1, float* __restrict__ as1,
                        float* __restrict__ ad1, int n) {
    __shared__ float w_lds[64 * 64];
    int t = threadIdx.x;
    for (int i = t; i < 4096; i += 256) w_lds[i] = W1[i];
    __syncthreads();
    int lane = t & 63, wid = t >> 6;
    int head = lane >> 5, cc = lane & 31;
    float asv = a_src1[head * 32 + cc], adv = a_dst1[head * 32 + cc];
    int nwaves = gridDim.x * 4;
    for (int node = blockIdx.x * 4 + wid; node < n; node += nwaves) {
        float xv = x[node * 64 + lane];
        float acc = 0.f;
#pragma unroll
        for (int k = 0; k < 64; ++k) {
            float xk = __shfl(xv, k, 64);
            acc = fmaf(xk, w_lds[k * 64 + lane], acc);
        }
        h1[node * 64 + lane] = acc;
        float ps = acc * asv, pd = acc * adv;
        for (int d = 16; d > 0; d >>= 1) { ps += __shfl_xor(ps, d, 64); pd += __shfl_xor(pd, d, 64); }
        if (cc == 0) { as1[node * 2 + head] = ps; ad1[node * 2 + head] = pd; }
    }
}

// Layer-1 aggregation + bias + exact GELU + (x2 @ W2) + layer-2 logits. One wave per node.
__global__ void k_agg1(const float* __restrict__ h1, const float* __restrict__ as1,
                       const float* __restrict__ ad1, const float* __restrict__ b1,
                       const float* __restrict__ W2, const float* __restrict__ a_src2,
                       const float* __restrict__ a_dst2,
                       const int* __restrict__ off, const int* __restrict__ csr_src,
                       float* __restrict__ h2lin, float* __restrict__ as2,
                       float* __restrict__ ad2, int n) {
    __shared__ float w2_lds[64 * 32];
    __shared__ float b1_lds[64];
    __shared__ float av2_lds[64];
    int t = threadIdx.x;
    for (int i = t; i < 2048; i += 256) w2_lds[i] = W2[i];
    if (t < 64) b1_lds[t] = b1[t];
    if (t < 32) av2_lds[t] = a_src2[t];
    else if (t < 64) av2_lds[t] = a_dst2[t - 32];
    __syncthreads();
    int lane = t & 63, wid = t >> 6;
    int head = lane >> 5, cc = lane & 31;
    int nwaves = gridDim.x * 4;
    for (int node = blockIdx.x * 4 + wid; node < n; node += nwaves) {
        float adh = ad1[node * 2 + head];
        float acc = 0.f, wsum = 0.f;
        int pe = off[node + 1];
        for (int p = off[node]; p < pe; ++p) {
            int s = csr_src[p];
            float e = as1[s * 2 + head] + adh;
            e = e > 0.f ? e : 0.2f * e;
            float w = __expf(e);
            wsum += w;
            acc = fmaf(w, h1[s * 64 + lane], acc);
        }
        float g = acc / wsum + b1_lds[lane];
        g = 0.5f * g * (1.0f + erff(g * 0.70710678118654752f));   // exact GELU
        // h2lin = gelu_out @ W2 via full-wave broadcast
        float acc2 = 0.f;
#pragma unroll
        for (int k = 0; k < 64; ++k) {
            float gk = __shfl(g, k, 64);
            acc2 = fmaf(gk, w2_lds[k * 32 + cc], acc2);
        }
        float ps = acc2 * av2_lds[cc];
        float pd = acc2 * av2_lds[32 + cc];
        for (int d = 16; d > 0; d >>= 1) { ps += __shfl_xor(ps, d, 64); pd += __shfl_xor(pd, d, 64); }
        if (lane < 32) h2lin[node * 32 + cc] = acc2;
        if (lane == 0) { as2[node] = ps; ad2[node] = pd; }
    }
}

// Layer-2 aggregation: one wave per node, two edges in flight (32 ch per half).
__global__ void k_agg2(const float* __restrict__ h2lin, const float* __restrict__ as2,
                       const float* __restrict__ ad2, const float* __restrict__ b2,
                       const int* __restrict__ off, const int* __restrict__ csr_src,
                       float* __restrict__ out, int n) {
    int t = threadIdx.x;
    int lane = t & 63, wid = t >> 6;
    int eh = lane >> 5, cc = lane & 31;
    int nwaves = gridDim.x * 4;
    for (int node = blockIdx.x * 4 + wid; node < n; node += nwaves) {
        float adv = ad2[node];
        float acc = 0.f, wsum = 0.f;
        int pe = off[node + 1];
        for (int p = off[node] + eh; p < pe; p += 2) {
            int s = csr_src[p];
            float e = as2[s] + adv;
            e = e > 0.f ? e : 0.2f * e;
            float w = __expf(e);
            wsum += w;
            acc = fmaf(w, h2lin[s * 32 + cc], acc);
        }
        acc += __shfl_xor(acc, 32, 64);
        wsum += __shfl_xor(wsum, 32, 64);
        if (lane < 32) out[node * 32 + cc] = acc / wsum + b2[cc];
    }
}

extern "C" void kernel_launch(void* const* d_in, const int* in_sizes, int n_in,
                              void* d_out, int out_size, void* d_ws, size_t ws_size,
                              hipStream_t stream) {
    const float* x      = (const float*)d_in[0];
    const int*   ei     = (const int*)d_in[1];
    const float* W1     = (const float*)d_in[2];
    const float* a_src1 = (const float*)d_in[3];
    const float* a_dst1 = (const float*)d_in[4];
    const float* b1     = (const float*)d_in[5];
    const float* W2     = (const float*)d_in[6];
    const float* a_src2 = (const float*)d_in[7];
    const float* a_dst2 = (const float*)d_in[8];
    const float* b2     = (const float*)d_in[9];
    float* out = (float*)d_out;

    int n   = in_sizes[0] / 64;
    int E   = in_sizes[1] / 2;
    int tot = E + n;

    char* w = (char*)d_ws;
    int* off  = (int*)w; w += sizeof(int) * (size_t)(n + 1);
    int* cnt  = (int*)w; w += sizeof(int) * (size_t)n;
    int* cur  = (int*)w; w += sizeof(int) * (size_t)n;
    int* bsum = (int*)w; w += sizeof(int) * 1024;
    int* csr  = (int*)w; w += sizeof(int) * (size_t)tot;
    float* h1  = (float*)w; w += sizeof(float) * (size_t)n * 64;
    float* as1 = (float*)w; w += sizeof(float) * (size_t)n * 2;
    float* ad1 = (float*)w; w += sizeof(float) * (size_t)n * 2;
    float* h2l = (float*)w; w += sizeof(float) * (size_t)n * 32;
    float* as2v = (float*)w; w += sizeof(float) * (size_t)n;
    float* ad2v = (float*)w; w += sizeof(float) * (size_t)n;

    k_init<<<(n + 255) / 256, 256, 0, stream>>>(cnt, cur, n);
    k_hist<<<(E + 255) / 256, 256, 0, stream>>>(ei, E, cnt);
    int nb = (n + 2047) / 2048;
    k_scan1<<<nb, 256, 0, stream>>>(cnt, off, bsum, n);
    k_scan2<<<1, 1024, 0, stream>>>(bsum, nb);
    k_scan3<<<(n + 255) / 256, 256, 0, stream>>>(off, bsum, n, tot);
    k_scatter<<<(tot + 255) / 256, 256, 0, stream>>>(ei, E, n, off, cur, csr);
    k_gemm1<<<1024, 256, 0, stream>>>(x, W1, a_src1, a_dst1, h1, as1, ad1, n);
    k_agg1<<<2048, 256, 0, stream>>>(h1, as1, ad1, b1, W2, a_src2, a_dst2,
                                     off, csr, h2l, as2v, ad2v, n);
    k_agg2<<<2048, 256, 0, stream>>>(h2l, as2v, ad2v, b2, off, csr, out, n);
}

// Round 2
// 481.951 us; speedup vs baseline: 1.4144x; 1.4144x over previous
//
#include <hip/hip_runtime.h>
#include <math.h>

// ---------------------------------------------------------------------------
// GAT 2-layer forward. N=100k nodes, E=1.6M edges + N self-loops.
// CSR-by-dst build (hist -> scan -> scatter), then per-node wave aggregation.
// R1: 4-edge ILP batching in both agg kernels to break the dependent
//     index->gather latency chain (agg1 was 324us at 12% HBM, 24% VALU).
// ---------------------------------------------------------------------------

__global__ void k_init(int* __restrict__ cnt, int* __restrict__ cur, int n) {
    int i = blockIdx.x * blockDim.x + threadIdx.x;
    if (i < n) { cnt[i] = 1; cur[i] = 0; }   // cnt starts at 1: self-loop
}

__global__ void k_hist(const int* __restrict__ ei, int E, int* __restrict__ cnt) {
    int i = blockIdx.x * blockDim.x + threadIdx.x;
    if (i < E) atomicAdd(&cnt[ei[E + i]], 1);     // ei[1][i] = dst
}

// Per-block (chunk=2048) exclusive scan, block totals to bsum.
__global__ void k_scan1(const int* __restrict__ cnt, int* __restrict__ off,
                        int* __restrict__ bsum, int n) {
    __shared__ int lds[256];
    int t = threadIdx.x;
    int base = blockIdx.x * 2048 + t * 8;
    int v[8]; int s = 0;
#pragma unroll
    for (int j = 0; j < 8; ++j) { int idx = base + j; v[j] = (idx < n) ? cnt[idx] : 0; s += v[j]; }
    lds[t] = s; __syncthreads();
    int inc = s;
    for (int d = 1; d < 256; d <<= 1) {
        int y = (t >= d) ? lds[t - d] : 0;
        __syncthreads();
        inc += y; lds[t] = inc;
        __syncthreads();
    }
    int run = inc - s;
#pragma unroll
    for (int j = 0; j < 8; ++j) { int idx = base + j; if (idx < n) off[idx] = run; run += v[j]; }
    if (t == 255) bsum[blockIdx.x] = inc;
}

__global__ void k_scan2(int* __restrict__ bsum, int nb) {
    __shared__ int lds[1024];
    int t = threadIdx.x;
    int v = (t < nb) ? bsum[t] : 0;
    lds[t] = v; __syncthreads();
    int inc = v;
    for (int d = 1; d < 1024; d <<= 1) {
        int y = (t >= d) ? lds[t - d] : 0;
        __syncthreads();
        inc += y; lds[t] = inc;
        __syncthreads();
    }
    if (t < nb) bsum[t] = inc - v;   // exclusive block prefix
}

__global__ void k_scan3(int* __restrict__ off, const int* __restrict__ bsum, int n, int total) {
    int i = blockIdx.x * blockDim.x + threadIdx.x;
    if (i < n) off[i] += bsum[i / 2048];
    if (i == 0) off[n] = total;
}

__global__ void k_scatter(const int* __restrict__ ei, int E, int n,
                          const int* __restrict__ off, int* __restrict__ cur,
                          int* __restrict__ csr_src) {
    int i = blockIdx.x * blockDim.x + threadIdx.x;
    int total = E + n;
    if (i >= total) return;
    int s, d;
    if (i < E) { s = ei[i]; d = ei[E + i]; } else { s = d = i - E; }
    int pos = off[d] + atomicAdd(&cur[d], 1);
    csr_src[pos] = s;
}

// h1 = x @ W1  [N,64]; also attention logit halves as1/ad1 [N,2].
__global__ void k_gemm1(const float* __restrict__ x, const float* __restrict__ W1,
                        const float* __restrict__ a_src1, const float* __restrict__ a_dst1,
                        float* __restrict__ h1, float* __restrict__ as1,
                        float* __restrict__ ad1, int n) {
    __shared__ float w_lds[64 * 64];
    int t = threadIdx.x;
    for (int i = t; i < 4096; i += 256) w_lds[i] = W1[i];
    __syncthreads();
    int lane = t & 63, wid = t >> 6;
    int head = lane >> 5, cc = lane & 31;
    float asv = a_src1[head * 32 + cc], adv = a_dst1[head * 32 + cc];
    int nwaves = gridDim.x * 4;
    for (int node = blockIdx.x * 4 + wid; node < n; node += nwaves) {
        float xv = x[node * 64 + lane];
        float acc = 0.f;
#pragma unroll
        for (int k = 0; k < 64; ++k) {
            float xk = __shfl(xv, k, 64);
            acc = fmaf(xk, w_lds[k * 64 + lane], acc);
        }
        h1[node * 64 + lane] = acc;
        float ps = acc * asv, pd = acc * adv;
        for (int d = 16; d > 0; d >>= 1) { ps += __shfl_xor(ps, d, 64); pd += __shfl_xor(pd, d, 64); }
        if (cc == 0) { as1[node * 2 + head] = ps; ad1[node * 2 + head] = pd; }
    }
}

// Layer-1 aggregation + bias + exact GELU + (x2 @ W2) + layer-2 logits.
// One wave per node; 4-edge ILP batching.
__global__ void k_agg1(const float* __restrict__ h1, const float* __restrict__ as1,
                       const float* __restrict__ ad1, const float* __restrict__ b1,
                       const float* __restrict__ W2, const float* __restrict__ a_src2,
                       const float* __restrict__ a_dst2,
                       const int* __restrict__ off, const int* __restrict__ csr_src,
                       float* __restrict__ h2lin, float* __restrict__ as2,
                       float* __restrict__ ad2, int n) {
    __shared__ float w2_lds[64 * 32];
    __shared__ float b1_lds[64];
    __shared__ float av2_lds[64];
    int t = threadIdx.x;
    for (int i = t; i < 2048; i += 256) w2_lds[i] = W2[i];
    if (t < 64) b1_lds[t] = b1[t];
    if (t < 32) av2_lds[t] = a_src2[t];
    else if (t < 64) av2_lds[t] = a_dst2[t - 32];
    __syncthreads();
    int lane = t & 63, wid = t >> 6;
    int head = lane >> 5, cc = lane & 31;
    int nwaves = gridDim.x * 4;
    for (int node = blockIdx.x * 4 + wid; node < n; node += nwaves) {
        float adh = ad1[node * 2 + head];
        float acc = 0.f, wsum = 0.f;
        int p = off[node], pe = off[node + 1];
        for (; p + 4 <= pe; p += 4) {
            int s0 = csr_src[p + 0];
            int s1 = csr_src[p + 1];
            int s2 = csr_src[p + 2];
            int s3 = csr_src[p + 3];
            float a0 = as1[s0 * 2 + head];
            float a1 = as1[s1 * 2 + head];
            float a2 = as1[s2 * 2 + head];
            float a3 = as1[s3 * 2 + head];
            float v0 = h1[s0 * 64 + lane];
            float v1 = h1[s1 * 64 + lane];
            float v2 = h1[s2 * 64 + lane];
            float v3 = h1[s3 * 64 + lane];
            float e0 = a0 + adh; e0 = e0 > 0.f ? e0 : 0.2f * e0;
            float e1 = a1 + adh; e1 = e1 > 0.f ? e1 : 0.2f * e1;
            float e2 = a2 + adh; e2 = e2 > 0.f ? e2 : 0.2f * e2;
            float e3 = a3 + adh; e3 = e3 > 0.f ? e3 : 0.2f * e3;
            float w0 = __expf(e0), w1 = __expf(e1), w2 = __expf(e2), w3 = __expf(e3);
            wsum += (w0 + w1) + (w2 + w3);
            acc = fmaf(w0, v0, acc);
            acc = fmaf(w1, v1, acc);
            acc = fmaf(w2, v2, acc);
            acc = fmaf(w3, v3, acc);
        }
        for (; p < pe; ++p) {
            int s = csr_src[p];
            float e = as1[s * 2 + head] + adh;
            e = e > 0.f ? e : 0.2f * e;
            float w = __expf(e);
            wsum += w;
            acc = fmaf(w, h1[s * 64 + lane], acc);
        }
        float g = acc / wsum + b1_lds[lane];
        g = 0.5f * g * (1.0f + erff(g * 0.70710678118654752f));   // exact GELU
        // h2lin = gelu_out @ W2 via full-wave broadcast
        float acc2 = 0.f;
#pragma unroll
        for (int k = 0; k < 64; ++k) {
            float gk = __shfl(g, k, 64);
            acc2 = fmaf(gk, w2_lds[k * 32 + cc], acc2);
        }
        float ps = acc2 * av2_lds[cc];
        float pd = acc2 * av2_lds[32 + cc];
        for (int d = 16; d > 0; d >>= 1) { ps += __shfl_xor(ps, d, 64); pd += __shfl_xor(pd, d, 64); }
        if (lane < 32) h2lin[node * 32 + cc] = acc2;
        if (lane == 0) { as2[node] = ps; ad2[node] = pd; }
    }
}

// Layer-2 aggregation: one wave per node, half-wave per edge stream,
// 4 edges per half-wave batch (8 edges in flight per wave).
__global__ void k_agg2(const float* __restrict__ h2lin, const float* __restrict__ as2,
                       const float* __restrict__ ad2, const float* __restrict__ b2,
                       const int* __restrict__ off, const int* __restrict__ csr_src,
                       float* __restrict__ out, int n) {
    int t = threadIdx.x;
    int lane = t & 63, wid = t >> 6;
    int eh = lane >> 5, cc = lane & 31;
    int nwaves = gridDim.x * 4;
    for (int node = blockIdx.x * 4 + wid; node < n; node += nwaves) {
        float adv = ad2[node];
        float acc = 0.f, wsum = 0.f;
        int p = off[node] + eh, pe = off[node + 1];
        for (; p + 6 < pe; p += 8) {
            int s0 = csr_src[p + 0];
            int s1 = csr_src[p + 2];
            int s2 = csr_src[p + 4];
            int s3 = csr_src[p + 6];
            float a0 = as2[s0];
            float a1 = as2[s1];
            float a2 = as2[s2];
            float a3 = as2[s3];
            float v0 = h2lin[s0 * 32 + cc];
            float v1 = h2lin[s1 * 32 + cc];
            float v2 = h2lin[s2 * 32 + cc];
            float v3 = h2lin[s3 * 32 + cc];
            float e0 = a0 + adv; e0 = e0 > 0.f ? e0 : 0.2f * e0;
            float e1 = a1 + adv; e1 = e1 > 0.f ? e1 : 0.2f * e1;
            float e2 = a2 + adv; e2 = e2 > 0.f ? e2 : 0.2f * e2;
            float e3 = a3 + adv; e3 = e3 > 0.f ? e3 : 0.2f * e3;
            float w0 = __expf(e0), w1 = __expf(e1), w2 = __expf(e2), w3 = __expf(e3);
            wsum += (w0 + w1) + (w2 + w3);
            acc = fmaf(w0, v0, acc);
            acc = fmaf(w1, v1, acc);
            acc = fmaf(w2, v2, acc);
            acc = fmaf(w3, v3, acc);
        }
        for (; p < pe; p += 2) {
            int s = csr_src[p];
            float e = as2[s] + adv;
            e = e > 0.f ? e : 0.2f * e;
            float w = __expf(e);
            wsum += w;
            acc = fmaf(w, h2lin[s * 32 + cc], acc);
        }
        acc += __shfl_xor(acc, 32, 64);
        wsum += __shfl_xor(wsum, 32, 64);
        if (lane < 32) out[node * 32 + cc] = acc / wsum + b2[cc];
    }
}

extern "C" void kernel_launch(void* const* d_in, const int* in_sizes, int n_in,
                              void* d_out, int out_size, void* d_ws, size_t ws_size,
                              hipStream_t stream) {
    const float* x      = (const float*)d_in[0];
    const int*   ei     = (const int*)d_in[1];
    const float* W1     = (const float*)d_in[2];
    const float* a_src1 = (const float*)d_in[3];
    const float* a_dst1 = (const float*)d_in[4];
    const float* b1     = (const float*)d_in[5];
    const float* W2     = (const float*)d_in[6];
    const float* a_src2 = (const float*)d_in[7];
    const float* a_dst2 = (const float*)d_in[8];
    const float* b2     = (const float*)d_in[9];
    float* out = (float*)d_out;

    int n   = in_sizes[0] / 64;
    int E   = in_sizes[1] / 2;
    int tot = E + n;

    char* w = (char*)d_ws;
    int* off  = (int*)w; w += sizeof(int) * (size_t)(n + 1);
    int* cnt  = (int*)w; w += sizeof(int) * (size_t)n;
    int* cur  = (int*)w; w += sizeof(int) * (size_t)n;
    int* bsum = (int*)w; w += sizeof(int) * 1024;
    int* csr  = (int*)w; w += sizeof(int) * (size_t)tot;
    float* h1  = (float*)w; w += sizeof(float) * (size_t)n * 64;
    float* as1 = (float*)w; w += sizeof(float) * (size_t)n * 2;
    float* ad1 = (float*)w; w += sizeof(float) * (size_t)n * 2;
    float* h2l = (float*)w; w += sizeof(float) * (size_t)n * 32;
    float* as2v = (float*)w; w += sizeof(float) * (size_t)n;
    float* ad2v = (float*)w; w += sizeof(float) * (size_t)n;

    k_init<<<(n + 255) / 256, 256, 0, stream>>>(cnt, cur, n);
    k_hist<<<(E + 255) / 256, 256, 0, stream>>>(ei, E, cnt);
    int nb = (n + 2047) / 2048;
    k_scan1<<<nb, 256, 0, stream>>>(cnt, off, bsum, n);
    k_scan2<<<1, 1024, 0, stream>>>(bsum, nb);
    k_scan3<<<(n + 255) / 256, 256, 0, stream>>>(off, bsum, n, tot);
    k_scatter<<<(tot + 255) / 256, 256, 0, stream>>>(ei, E, n, off, cur, csr);
    k_gemm1<<<1024, 256, 0, stream>>>(x, W1, a_src1, a_dst1, h1, as1, ad1, n);
    k_agg1<<<2048, 256, 0, stream>>>(h1, as1, ad1, b1, W2, a_src2, a_dst2,
                                     off, csr, h2l, as2v, ad2v, n);
    k_agg2<<<2048, 256, 0, stream>>>(h2l, as2v, ad2v, b2, off, csr, out, n);
}